// Round 12
// baseline (291.648 us; speedup 1.0000x reference)
//
#include <hip/hip_runtime.h>
#include <hip/hip_fp16.h>
#include <math.h>

#define N_NODES 100000
#define N_EDGES 3200000
#define IN_DIM 11
#define HID 32
#define HID2 16
#define SCHUNK 100352   // per-array stride in ws (multiple of 128)
#define BINSHIFT 8
#define BINSZ 256
#define NB 391          // ceil(100000/256)
#define CHUNK 8192      // edges per block in hist/scatter (391 blocks)

// ---------------- binned CSR build (exact counts; prefix computed in-block) ----------------
__global__ __launch_bounds__(1024) void k_hist(const int* __restrict__ ei,
                                               int* __restrict__ bincnt) {
    __shared__ int h[NB];
    for (int i = threadIdx.x; i < NB; i += 1024) h[i] = 0;
    __syncthreads();
    int b0 = blockIdx.x * CHUNK;
    int e1 = b0 + CHUNK; if (e1 > N_EDGES) e1 = N_EDGES;
    for (int e = b0 + threadIdx.x; e < e1; e += 1024)
        atomicAdd(&h[ei[N_EDGES + e] >> BINSHIFT], 1);
    __syncthreads();
    for (int i = threadIdx.x; i < NB; i += 1024)
        if (h[i]) atomicAdd(&bincnt[i], h[i]);
}

__global__ __launch_bounds__(1024) void k_binscatter(const int* __restrict__ ei,
                                                     const int* __restrict__ bincnt,
                                                     int* __restrict__ bincur,
                                                     unsigned* __restrict__ binbuf) {
    __shared__ int pre[NB];
    __shared__ int h[NB];
    __shared__ int base[NB];
    __shared__ int tmp[512];
    int tid = threadIdx.x;
    int v = (tid < NB) ? bincnt[tid] : 0;
    if (tid < 512) tmp[tid] = v;
    __syncthreads();
    for (int off = 1; off < 512; off <<= 1) {
        int t = (tid < 512 && tid >= off) ? tmp[tid - off] : 0;
        __syncthreads();
        if (tid < 512) tmp[tid] += t;
        __syncthreads();
    }
    if (tid < NB) pre[tid] = tmp[tid] - v;
    for (int i = tid; i < NB; i += 1024) h[i] = 0;
    __syncthreads();
    int b0 = blockIdx.x * CHUNK;
    int e1 = b0 + CHUNK; if (e1 > N_EDGES) e1 = N_EDGES;
    for (int e = b0 + tid; e < e1; e += 1024)
        atomicAdd(&h[ei[N_EDGES + e] >> BINSHIFT], 1);
    __syncthreads();
    for (int i = tid; i < NB; i += 1024) {
        int c = h[i];
        if (c) base[i] = pre[i] + atomicAdd(&bincur[i], c);
        h[i] = 0;
    }
    __syncthreads();
    for (int e = b0 + tid; e < e1; e += 1024) {
        int d = ei[N_EDGES + e];
        int s = ei[e];
        int b = d >> BINSHIFT;
        int p = base[b] + atomicAdd(&h[b], 1);
        binbuf[p] = (unsigned)s | ((unsigned)(d & (BINSZ - 1)) << 17);  // s < 2^17
    }
}

__global__ __launch_bounds__(1024) void k_binfill(const unsigned* __restrict__ binbuf,
                                                  const int* __restrict__ bincnt,
                                                  int* __restrict__ rowstart,
                                                  float* __restrict__ dinv,
                                                  int* __restrict__ csr_src) {
    int b = blockIdx.x;
    int tid = threadIdx.x;
    __shared__ int tmp[512];
    __shared__ int cnt[BINSZ];
    __shared__ int rloc[BINSZ];
    __shared__ int cur[BINSZ];
    int v = (tid < 512 && tid < b) ? bincnt[tid] : 0;
    if (tid < 512) tmp[tid] = v;
    __syncthreads();
    for (int off = 256; off >= 1; off >>= 1) {
        if (tid < off) tmp[tid] += tmp[tid + off];
        __syncthreads();
    }
    int ebeg = tmp[0];
    int eend = ebeg + bincnt[b];
    __syncthreads();
    if (tid < BINSZ) cnt[tid] = 0;
    __syncthreads();
    for (int e = ebeg + tid; e < eend; e += 1024)
        atomicAdd(&cnt[binbuf[e] >> 17], 1);
    __syncthreads();
    int c = (tid < BINSZ) ? cnt[tid] : 0;
    if (tid < BINSZ) tmp[tid] = c;
    __syncthreads();
    for (int off = 1; off < BINSZ; off <<= 1) {
        int t = (tid < BINSZ && tid >= off) ? tmp[tid - off] : 0;
        __syncthreads();
        if (tid < BINSZ) tmp[tid] += t;
        __syncthreads();
    }
    if (tid < BINSZ) {
        rloc[tid] = tmp[tid] - c;
        cur[tid] = 0;
        int node = b * BINSZ + tid;
        if (node < N_NODES) {
            rowstart[node] = ebeg + rloc[tid];
            dinv[node] = rsqrtf((float)c + 1.0f);  // +1 self-loop
        }
    }
    if (b == 0 && tid == 0) rowstart[N_NODES] = N_EDGES;  // sentinel
    __syncthreads();
    for (int e = ebeg + tid; e < eend; e += 1024) {
        unsigned vv = binbuf[e];
        int dl = vv >> 17;
        int s = (int)(vv & 0x1FFFFu);
        int p = ebeg + rloc[dl] + atomicAdd(&cur[dl], 1);
        csr_src[p] = s;
    }
}

// ---------------- dense transform 1 (write dinv-scaled fp16, interleaved [node*32+j]) -----
__global__ void k_xw1(const float* __restrict__ x, const float* __restrict__ W1,
                      const float* __restrict__ dinv, __half* __restrict__ xwh) {
    int t = blockIdx.x * blockDim.x + threadIdx.x;
    int node = t >> 5;
    int j = t & 31;
    __shared__ float sW[IN_DIM * HID];
    __shared__ float sx[8 * IN_DIM];
    for (int i = threadIdx.x; i < IN_DIM * HID; i += 256) sW[i] = W1[i];
    int base = blockIdx.x * 8;
    if (threadIdx.x < 8 * IN_DIM) sx[threadIdx.x] = x[base * IN_DIM + threadIdx.x];
    __syncthreads();
    int ln = node - base;
    float acc = 0.0f;
#pragma unroll
    for (int k = 0; k < IN_DIM; ++k)
        acc += sx[ln * IN_DIM + k] * sW[k * HID + j];
    xwh[t] = __float2half(dinv[node] * acc);
}

// shared edge-accumulate body (int4 index loads, 8-row unroll)
__device__ __forceinline__ float edge_accum(int beg, int end, int j,
                                            const int* __restrict__ csr_src,
                                            const __half* __restrict__ xwh) {
    float acc = 0.0f;
    int e = beg;
    while (e < end && (e & 3)) {  // align to 16B for int4 loads
        acc += __half2float(xwh[csr_src[e] * HID + j]);
        ++e;
    }
    for (; e + 8 <= end; e += 8) {
        int4 i0 = *(const int4*)(csr_src + e);
        int4 i1 = *(const int4*)(csr_src + e + 4);
        float x0 = __half2float(xwh[i0.x * HID + j]);
        float x1 = __half2float(xwh[i0.y * HID + j]);
        float x2 = __half2float(xwh[i0.z * HID + j]);
        float x3 = __half2float(xwh[i0.w * HID + j]);
        float x4 = __half2float(xwh[i1.x * HID + j]);
        float x5 = __half2float(xwh[i1.y * HID + j]);
        float x6 = __half2float(xwh[i1.z * HID + j]);
        float x7 = __half2float(xwh[i1.w * HID + j]);
        acc += ((x0 + x1) + (x2 + x3)) + ((x4 + x5) + (x6 + x7));
    }
    if (e + 4 <= end) {
        int4 i0 = *(const int4*)(csr_src + e);
        acc += (__half2float(xwh[i0.x * HID + j]) + __half2float(xwh[i0.y * HID + j])) +
               (__half2float(xwh[i0.z * HID + j]) + __half2float(xwh[i0.w * HID + j]));
        e += 4;
    }
    for (; e < end; ++e)
        acc += __half2float(xwh[csr_src[e] * HID + j]);
    return acc;
}

// ---------------- layer-1 gather fused with bias1+relu and the W2 transform ---------------
// grid exactly N_NODES/8 blocks (no early returns -> barriers safe)
__global__ __launch_bounds__(256) void k_gather_xw2(const int* __restrict__ rowstart,
                                                    const float* __restrict__ dinv,
                                                    const int* __restrict__ csr_src,
                                                    const __half* __restrict__ xwh1,
                                                    const float* __restrict__ b1,
                                                    const float* __restrict__ W2,
                                                    __half* __restrict__ xwh2) {
    __shared__ float sW2[HID * HID];
    __shared__ float sH[8 * 33];
    for (int i = threadIdx.x; i < HID * HID; i += 256) sW2[i] = W2[i];
    __syncthreads();

    int ln = threadIdx.x >> 5;
    int node = blockIdx.x * 8 + ln;
    int j = threadIdx.x & 31;
    float acc = edge_accum(rowstart[node], rowstart[node + 1], j, csr_src, xwh1);
    float dd = dinv[node];
    float hv = dd * (acc + __half2float(xwh1[node * HID + j])) + b1[j];
    sH[ln * 33 + j] = hv > 0.0f ? hv : 0.0f;  // H = relu(agg + b1)
    __syncthreads();

    // XWH2[node][j] = fp16( dinv[node] * sum_k H[k] * W2[k][j] )
    float a2 = 0.0f;
#pragma unroll
    for (int k = 0; k < HID; ++k) a2 += sH[ln * 33 + k] * sW2[k * HID + j];
    xwh2[node * HID + j] = __float2half(dd * a2);
}

// ---------------- layer-2 gather fused with bias2+relu and the output MLP ----------------
__global__ __launch_bounds__(256) void k_gather_mlp(const int* __restrict__ rowstart,
                                                    const float* __restrict__ dinv,
                                                    const int* __restrict__ csr_src,
                                                    const __half* __restrict__ xwh,
                                                    const float* __restrict__ b2,
                                                    const float* __restrict__ Wo1,
                                                    const float* __restrict__ bo1,
                                                    const float* __restrict__ Wo2,
                                                    const float* __restrict__ bo2,
                                                    float* __restrict__ out) {
    __shared__ float sW1[HID * HID2];
    __shared__ float sb1[HID2];
    __shared__ float sW2[HID2];
    __shared__ float sb2[HID];
    __shared__ float sH[8 * 33];
    for (int i = threadIdx.x; i < HID * HID2; i += 256) sW1[i] = Wo1[i];
    if (threadIdx.x < HID2) {
        sb1[threadIdx.x] = bo1[threadIdx.x];
        sW2[threadIdx.x] = Wo2[threadIdx.x];
    }
    if (threadIdx.x < HID) sb2[threadIdx.x] = b2[threadIdx.x];
    __syncthreads();  // staging visible to all waves (fixes r11 latent race)

    int ln = threadIdx.x >> 5;
    int node = blockIdx.x * 8 + ln;
    int j = threadIdx.x & 31;
    float acc = edge_accum(rowstart[node], rowstart[node + 1], j, csr_src, xwh);
    float dd = dinv[node];
    float hv = dd * (acc + __half2float(xwh[node * HID + j])) + sb2[j];
    sH[ln * 33 + j] = hv > 0.0f ? hv : 0.0f;  // relu(agg + b2)
    __syncthreads();

    float val = 0.0f;
    if (j < HID2) {
        float a = sb1[j];
#pragma unroll
        for (int k = 0; k < HID; ++k) a += sH[ln * 33 + k] * sW1[k * HID2 + j];
        a = a > 0.0f ? a : (expf(a) - 1.0f);  // elu alpha=1
        val = a * sW2[j];
    }
#pragma unroll
    for (int d = 16; d >= 1; d >>= 1) val += __shfl_down(val, d, 32);
    if (j == 0) out[node] = val + bo2[0];
}

extern "C" void kernel_launch(void* const* d_in, const int* in_sizes, int n_in,
                              void* d_out, int out_size, void* d_ws, size_t ws_size,
                              hipStream_t stream) {
    const float* x   = (const float*)d_in[0];
    const int*   ei  = (const int*)d_in[1];
    const float* W1  = (const float*)d_in[3];
    const float* b1  = (const float*)d_in[4];
    const float* W2  = (const float*)d_in[5];
    const float* b2  = (const float*)d_in[6];
    const float* Wo1 = (const float*)d_in[7];
    const float* bo1 = (const float*)d_in[8];
    const float* Wo2 = (const float*)d_in[9];
    const float* bo2 = (const float*)d_in[10];
    float* out = (float*)d_out;

    // ws layout (4B units):
    // bincnt[512] | bincur[512] | rowstart[SCHUNK] | dinv[SCHUNK]
    // | csr_src[E] | binbuf[E] | XWH1[N*HID fp16] | XWH2[N*HID fp16]
    int*      bincnt   = (int*)d_ws;
    int*      bincur   = bincnt + 512;
    int*      rowstart = bincur + 512;
    float*    dinv     = (float*)(rowstart + SCHUNK);
    int*      csr_src  = (int*)(dinv + SCHUNK);
    unsigned* binbuf   = (unsigned*)(csr_src + N_EDGES);
    __half*   XWH1     = (__half*)(binbuf + N_EDGES);
    __half*   XWH2     = XWH1 + (size_t)N_NODES * HID;

    const int BT = 256;
    int gNH  = (N_NODES * HID + BT - 1) / BT;       // 12500
    int gC   = (N_EDGES + CHUNK - 1) / CHUNK;       // 391
    int gG   = N_NODES / 8;                         // 12500 (exact)

    // binned CSR build (rowstart, dinv, csr_src)
    hipMemsetAsync(bincnt, 0, 1024 * sizeof(int), stream);  // bincnt + bincur
    k_hist      <<<gC, 1024, 0, stream>>>(ei, bincnt);
    k_binscatter<<<gC, 1024, 0, stream>>>(ei, bincnt, bincur, binbuf);
    k_binfill   <<<NB, 1024, 0, stream>>>(binbuf, bincnt, rowstart, dinv, csr_src);

    // layer 1 (+ fused W2): XWH1 = fp16(dinv.*(x@W1)); XWH2 = fp16(dinv.*(relu(gather+b1)@W2))
    k_xw1<<<gNH, BT, 0, stream>>>(x, W1, dinv, XWH1);
    k_gather_xw2<<<gG, BT, 0, stream>>>(rowstart, dinv, csr_src, XWH1, b1, W2, XWH2);

    // layer 2 + head: out = MLP(relu(dinv.*gather(XWH2) + b2))
    k_gather_mlp<<<gG, BT, 0, stream>>>(rowstart, dinv, csr_src, XWH2,
                                        b2, Wo1, bo1, Wo2, bo2, out);
}

// Round 13
// 271.334 us; speedup vs baseline: 1.0749x; 1.0749x over previous
//
#include <hip/hip_runtime.h>
#include <hip/hip_fp16.h>
#include <math.h>

#define N_NODES 100000
#define N_EDGES 3200000
#define IN_DIM 11
#define HID 32
#define HID2 16
#define SCHUNK 100352   // per-array stride in ws (multiple of 128)
#define BINSHIFT 8
#define BINSZ 256
#define NB 391          // ceil(100000/256)
#define CHUNK 8192      // edges per block in hist/scatter (391 blocks)

// ---------------- binned CSR build (exact counts; prefix computed in-block) ----------------
__global__ __launch_bounds__(1024) void k_hist(const int* __restrict__ ei,
                                               int* __restrict__ bincnt) {
    __shared__ int h[NB];
    for (int i = threadIdx.x; i < NB; i += 1024) h[i] = 0;
    __syncthreads();
    int b0 = blockIdx.x * CHUNK;
    int e1 = b0 + CHUNK; if (e1 > N_EDGES) e1 = N_EDGES;
    for (int e = b0 + threadIdx.x; e < e1; e += 1024)
        atomicAdd(&h[ei[N_EDGES + e] >> BINSHIFT], 1);
    __syncthreads();
    for (int i = threadIdx.x; i < NB; i += 1024)
        if (h[i]) atomicAdd(&bincnt[i], h[i]);
}

__global__ __launch_bounds__(1024) void k_binscatter(const int* __restrict__ ei,
                                                     const int* __restrict__ bincnt,
                                                     int* __restrict__ bincur,
                                                     unsigned* __restrict__ binbuf) {
    __shared__ int pre[NB];
    __shared__ int h[NB];
    __shared__ int base[NB];
    __shared__ int tmp[512];
    int tid = threadIdx.x;
    int v = (tid < NB) ? bincnt[tid] : 0;
    if (tid < 512) tmp[tid] = v;
    __syncthreads();
    for (int off = 1; off < 512; off <<= 1) {
        int t = (tid < 512 && tid >= off) ? tmp[tid - off] : 0;
        __syncthreads();
        if (tid < 512) tmp[tid] += t;
        __syncthreads();
    }
    if (tid < NB) pre[tid] = tmp[tid] - v;
    for (int i = tid; i < NB; i += 1024) h[i] = 0;
    __syncthreads();
    int b0 = blockIdx.x * CHUNK;
    int e1 = b0 + CHUNK; if (e1 > N_EDGES) e1 = N_EDGES;
    for (int e = b0 + tid; e < e1; e += 1024)
        atomicAdd(&h[ei[N_EDGES + e] >> BINSHIFT], 1);
    __syncthreads();
    for (int i = tid; i < NB; i += 1024) {
        int c = h[i];
        if (c) base[i] = pre[i] + atomicAdd(&bincur[i], c);
        h[i] = 0;
    }
    __syncthreads();
    for (int e = b0 + tid; e < e1; e += 1024) {
        int d = ei[N_EDGES + e];
        int s = ei[e];
        int b = d >> BINSHIFT;
        int p = base[b] + atomicAdd(&h[b], 1);
        binbuf[p] = (unsigned)s | ((unsigned)(d & (BINSZ - 1)) << 17);  // s < 2^17
    }
}

__global__ __launch_bounds__(1024) void k_binfill(const unsigned* __restrict__ binbuf,
                                                  const int* __restrict__ bincnt,
                                                  int* __restrict__ rowstart,
                                                  float* __restrict__ dinv,
                                                  int* __restrict__ csr_src) {
    int b = blockIdx.x;
    int tid = threadIdx.x;
    __shared__ int tmp[512];
    __shared__ int cnt[BINSZ];
    __shared__ int rloc[BINSZ];
    __shared__ int cur[BINSZ];
    int v = (tid < 512 && tid < b) ? bincnt[tid] : 0;
    if (tid < 512) tmp[tid] = v;
    __syncthreads();
    for (int off = 256; off >= 1; off >>= 1) {
        if (tid < off) tmp[tid] += tmp[tid + off];
        __syncthreads();
    }
    int ebeg = tmp[0];
    int eend = ebeg + bincnt[b];
    __syncthreads();
    if (tid < BINSZ) cnt[tid] = 0;
    __syncthreads();
    for (int e = ebeg + tid; e < eend; e += 1024)
        atomicAdd(&cnt[binbuf[e] >> 17], 1);
    __syncthreads();
    int c = (tid < BINSZ) ? cnt[tid] : 0;
    if (tid < BINSZ) tmp[tid] = c;
    __syncthreads();
    for (int off = 1; off < BINSZ; off <<= 1) {
        int t = (tid < BINSZ && tid >= off) ? tmp[tid - off] : 0;
        __syncthreads();
        if (tid < BINSZ) tmp[tid] += t;
        __syncthreads();
    }
    if (tid < BINSZ) {
        rloc[tid] = tmp[tid] - c;
        cur[tid] = 0;
        int node = b * BINSZ + tid;
        if (node < N_NODES) {
            rowstart[node] = ebeg + rloc[tid];
            dinv[node] = rsqrtf((float)c + 1.0f);  // +1 self-loop
        }
    }
    if (b == 0 && tid == 0) rowstart[N_NODES] = N_EDGES;  // sentinel
    __syncthreads();
    for (int e = ebeg + tid; e < eend; e += 1024) {
        unsigned vv = binbuf[e];
        int dl = vv >> 17;
        int s = (int)(vv & 0x1FFFFu);
        int p = ebeg + rloc[dl] + atomicAdd(&cur[dl], 1);
        csr_src[p] = s;
    }
}

// ---------------- dense transform 1 (write dinv-scaled fp16, interleaved [node*32+j]) -----
__global__ void k_xw1(const float* __restrict__ x, const float* __restrict__ W1,
                      const float* __restrict__ dinv, __half* __restrict__ xwh) {
    int t = blockIdx.x * blockDim.x + threadIdx.x;
    int node = t >> 5;
    int j = t & 31;
    __shared__ float sW[IN_DIM * HID];
    __shared__ float sx[8 * IN_DIM];
    for (int i = threadIdx.x; i < IN_DIM * HID; i += 256) sW[i] = W1[i];
    int base = blockIdx.x * 8;
    if (threadIdx.x < 8 * IN_DIM) sx[threadIdx.x] = x[base * IN_DIM + threadIdx.x];
    __syncthreads();
    int ln = node - base;
    float acc = 0.0f;
#pragma unroll
    for (int k = 0; k < IN_DIM; ++k)
        acc += sx[ln * IN_DIM + k] * sW[k * HID + j];
    xwh[t] = __float2half(dinv[node] * acc);
}

// shared edge-accumulate body: scalar index loads (schedulable independently),
// 16-deep unroll for high miss-level parallelism
__device__ __forceinline__ float edge_accum(int beg, int end, int j,
                                            const int* __restrict__ csr_src,
                                            const __half* __restrict__ xwh) {
    float acc = 0.0f;
    int e = beg;
    for (; e + 16 <= end; e += 16) {
        int s[16];
#pragma unroll
        for (int u = 0; u < 16; ++u) s[u] = csr_src[e + u];
        float xv[16];
#pragma unroll
        for (int u = 0; u < 16; ++u) xv[u] = __half2float(xwh[s[u] * HID + j]);
        float a0 = ((xv[0] + xv[1]) + (xv[2] + xv[3])) + ((xv[4] + xv[5]) + (xv[6] + xv[7]));
        float a1 = ((xv[8] + xv[9]) + (xv[10] + xv[11])) + ((xv[12] + xv[13]) + (xv[14] + xv[15]));
        acc += a0 + a1;
    }
    if (e + 8 <= end) {
        int s0 = csr_src[e],     s1 = csr_src[e + 1], s2 = csr_src[e + 2], s3 = csr_src[e + 3];
        int s4 = csr_src[e + 4], s5 = csr_src[e + 5], s6 = csr_src[e + 6], s7 = csr_src[e + 7];
        float x0 = __half2float(xwh[s0 * HID + j]);
        float x1 = __half2float(xwh[s1 * HID + j]);
        float x2 = __half2float(xwh[s2 * HID + j]);
        float x3 = __half2float(xwh[s3 * HID + j]);
        float x4 = __half2float(xwh[s4 * HID + j]);
        float x5 = __half2float(xwh[s5 * HID + j]);
        float x6 = __half2float(xwh[s6 * HID + j]);
        float x7 = __half2float(xwh[s7 * HID + j]);
        acc += ((x0 + x1) + (x2 + x3)) + ((x4 + x5) + (x6 + x7));
        e += 8;
    }
    for (; e + 2 <= end; e += 2) {
        int s0 = csr_src[e], s1 = csr_src[e + 1];
        acc += __half2float(xwh[s0 * HID + j]) + __half2float(xwh[s1 * HID + j]);
    }
    for (; e < end; ++e)
        acc += __half2float(xwh[csr_src[e] * HID + j]);
    return acc;
}

// ---------------- layer-1 gather fused with bias1+relu and the W2 transform ---------------
// grid exactly N_NODES/8 blocks (no early returns -> barriers safe)
__global__ __launch_bounds__(256) void k_gather_xw2(const int* __restrict__ rowstart,
                                                    const float* __restrict__ dinv,
                                                    const int* __restrict__ csr_src,
                                                    const __half* __restrict__ xwh1,
                                                    const float* __restrict__ b1,
                                                    const float* __restrict__ W2,
                                                    __half* __restrict__ xwh2) {
    __shared__ float sW2[HID * HID];
    __shared__ float sH[8 * 33];
    for (int i = threadIdx.x; i < HID * HID; i += 256) sW2[i] = W2[i];
    __syncthreads();

    int ln = threadIdx.x >> 5;
    int node = blockIdx.x * 8 + ln;
    int j = threadIdx.x & 31;
    float acc = edge_accum(rowstart[node], rowstart[node + 1], j, csr_src, xwh1);
    float dd = dinv[node];
    float hv = dd * (acc + __half2float(xwh1[node * HID + j])) + b1[j];
    sH[ln * 33 + j] = hv > 0.0f ? hv : 0.0f;  // H = relu(agg + b1)
    __syncthreads();

    // XWH2[node][j] = fp16( dinv[node] * sum_k H[k] * W2[k][j] )
    float a2 = 0.0f;
#pragma unroll
    for (int k = 0; k < HID; ++k) a2 += sH[ln * 33 + k] * sW2[k * HID + j];
    xwh2[node * HID + j] = __float2half(dd * a2);
}

// ---------------- layer-2 gather fused with bias2+relu and the output MLP ----------------
__global__ __launch_bounds__(256) void k_gather_mlp(const int* __restrict__ rowstart,
                                                    const float* __restrict__ dinv,
                                                    const int* __restrict__ csr_src,
                                                    const __half* __restrict__ xwh,
                                                    const float* __restrict__ b2,
                                                    const float* __restrict__ Wo1,
                                                    const float* __restrict__ bo1,
                                                    const float* __restrict__ Wo2,
                                                    const float* __restrict__ bo2,
                                                    float* __restrict__ out) {
    __shared__ float sW1[HID * HID2];
    __shared__ float sb1[HID2];
    __shared__ float sW2[HID2];
    __shared__ float sb2[HID];
    __shared__ float sH[8 * 33];
    for (int i = threadIdx.x; i < HID * HID2; i += 256) sW1[i] = Wo1[i];
    if (threadIdx.x < HID2) {
        sb1[threadIdx.x] = bo1[threadIdx.x];
        sW2[threadIdx.x] = Wo2[threadIdx.x];
    }
    if (threadIdx.x < HID) sb2[threadIdx.x] = b2[threadIdx.x];
    __syncthreads();  // staging visible to all waves

    int ln = threadIdx.x >> 5;
    int node = blockIdx.x * 8 + ln;
    int j = threadIdx.x & 31;
    float acc = edge_accum(rowstart[node], rowstart[node + 1], j, csr_src, xwh);
    float dd = dinv[node];
    float hv = dd * (acc + __half2float(xwh[node * HID + j])) + sb2[j];
    sH[ln * 33 + j] = hv > 0.0f ? hv : 0.0f;  // relu(agg + b2)
    __syncthreads();

    float val = 0.0f;
    if (j < HID2) {
        float a = sb1[j];
#pragma unroll
        for (int k = 0; k < HID; ++k) a += sH[ln * 33 + k] * sW1[k * HID2 + j];
        a = a > 0.0f ? a : (expf(a) - 1.0f);  // elu alpha=1
        val = a * sW2[j];
    }
#pragma unroll
    for (int d = 16; d >= 1; d >>= 1) val += __shfl_down(val, d, 32);
    if (j == 0) out[node] = val + bo2[0];
}

extern "C" void kernel_launch(void* const* d_in, const int* in_sizes, int n_in,
                              void* d_out, int out_size, void* d_ws, size_t ws_size,
                              hipStream_t stream) {
    const float* x   = (const float*)d_in[0];
    const int*   ei  = (const int*)d_in[1];
    const float* W1  = (const float*)d_in[3];
    const float* b1  = (const float*)d_in[4];
    const float* W2  = (const float*)d_in[5];
    const float* b2  = (const float*)d_in[6];
    const float* Wo1 = (const float*)d_in[7];
    const float* bo1 = (const float*)d_in[8];
    const float* Wo2 = (const float*)d_in[9];
    const float* bo2 = (const float*)d_in[10];
    float* out = (float*)d_out;

    // ws layout (4B units):
    // bincnt[512] | bincur[512] | rowstart[SCHUNK] | dinv[SCHUNK]
    // | csr_src[E] | binbuf[E] | XWH1[N*HID fp16] | XWH2[N*HID fp16]
    int*      bincnt   = (int*)d_ws;
    int*      bincur   = bincnt + 512;
    int*      rowstart = bincur + 512;
    float*    dinv     = (float*)(rowstart + SCHUNK);
    int*      csr_src  = (int*)(dinv + SCHUNK);
    unsigned* binbuf   = (unsigned*)(csr_src + N_EDGES);
    __half*   XWH1     = (__half*)(binbuf + N_EDGES);
    __half*   XWH2     = XWH1 + (size_t)N_NODES * HID;

    const int BT = 256;
    int gNH  = (N_NODES * HID + BT - 1) / BT;       // 12500
    int gC   = (N_EDGES + CHUNK - 1) / CHUNK;       // 391
    int gG   = N_NODES / 8;                         // 12500 (exact)

    // binned CSR build (rowstart, dinv, csr_src)
    hipMemsetAsync(bincnt, 0, 1024 * sizeof(int), stream);  // bincnt + bincur
    k_hist      <<<gC, 1024, 0, stream>>>(ei, bincnt);
    k_binscatter<<<gC, 1024, 0, stream>>>(ei, bincnt, bincur, binbuf);
    k_binfill   <<<NB, 1024, 0, stream>>>(binbuf, bincnt, rowstart, dinv, csr_src);

    // layer 1 (+ fused W2): XWH1 = fp16(dinv.*(x@W1)); XWH2 = fp16(dinv.*(relu(gather+b1)@W2))
    k_xw1<<<gNH, BT, 0, stream>>>(x, W1, dinv, XWH1);
    k_gather_xw2<<<gG, BT, 0, stream>>>(rowstart, dinv, csr_src, XWH1, b1, W2, XWH2);

    // layer 2 + head: out = MLP(relu(dinv.*gather(XWH2) + b2))
    k_gather_mlp<<<gG, BT, 0, stream>>>(rowstart, dinv, csr_src, XWH2,
                                        b2, Wo1, bo1, Wo2, bo2, out);
}